// Round 1
// baseline (689.742 us; speedup 1.0000x reference)
//
#include <hip/hip_runtime.h>
#include <math.h>

// Problem constants (from reference setup_inputs)
#define NSRC 8          // N-1 source frames
#define CCH  32         // channels
#define HH   192
#define WW   256
#define SS   9
#define GG   8

// f strides in floats: (N, C, H, W, S) contiguous
#define F_SC (HH*WW*SS)        // 442368
#define F_SH (WW*SS)           // 2304
#define F_SN (CCH*HH*WW*SS)    // 14155776

// workspace layout (floats)
#define WS_M   0      // 32x32  M' = Wp^T Wp / sqrt(C)
#define WS_V   1024   // 32     v' = Wp^T bp / sqrt(C)
#define WS_BB  1056   // 1      bb' = |bp|^2 / sqrt(C)
#define WS_ATT 1064   // 192*256*9 attention weights

// ---------------------------------------------------------------------------
// k0: tiny precompute of M', v', bb'
// ---------------------------------------------------------------------------
__global__ void k0_precompute(const float* __restrict__ Wp,
                              const float* __restrict__ bp,
                              float* __restrict__ ws) {
    const float inv_sqrtC = 0.17677669529663687f;  // 1/sqrt(32)
    int t = threadIdx.x;
    for (int idx = t; idx < 1024; idx += 256) {
        int c = idx >> 5, c2 = idx & 31;
        float acc = 0.f;
        for (int d = 0; d < 32; ++d) acc = fmaf(Wp[d*32 + c], Wp[d*32 + c2], acc);
        ws[WS_M + idx] = acc * inv_sqrtC;
    }
    if (t < 32) {
        float acc = 0.f;
        for (int d = 0; d < 32; ++d) acc = fmaf(Wp[d*32 + t], bp[d], acc);
        ws[WS_V + t] = acc * inv_sqrtC;
    }
    if (t == 0) {
        float acc = 0.f;
        for (int d = 0; d < 32; ++d) acc = fmaf(bp[d], bp[d], acc);
        ws[WS_BB] = acc * inv_sqrtC;
    }
}

// ---------------------------------------------------------------------------
// k1: per-pixel attention weights.
// logits[s] = u . ref[:,s] + beta  with u = M' r4 + v', beta = r4.v' + bb'
// ---------------------------------------------------------------------------
__global__ __launch_bounds__(64) void k1_att(const float* __restrict__ f,
                                             const float* __restrict__ ws,
                                             float* __restrict__ att_out) {
    int p = blockIdx.x * 64 + threadIdx.x;   // pixel id 0..49151
    int h = p >> 8;
    int w = p & 255;
    const long base = (long)h * F_SH + (long)w * SS;

    // u = v'; beta = bb'  (uniform scalar loads)
    float u[32];
    #pragma unroll
    for (int c = 0; c < 32; ++c) u[c] = ws[WS_V + c];
    float beta = ws[WS_BB];

    // u += M' r4 ; beta += r4 . v'
    for (int cp = 0; cp < 32; ++cp) {
        float r4 = f[(long)cp * F_SC + base + 4];
        beta = fmaf(r4, ws[WS_V + cp], beta);
        #pragma unroll
        for (int c = 0; c < 32; ++c)
            u[c] = fmaf(ws[WS_M + c * 32 + cp], r4, u[c]);
    }

    // logits
    float lg[SS];
    #pragma unroll
    for (int s = 0; s < SS; ++s) lg[s] = beta;
    for (int c = 0; c < 32; ++c) {
        const float* rrow = f + (long)c * F_SC + base;
        float uc = u[c];
        #pragma unroll
        for (int s = 0; s < SS; ++s) lg[s] = fmaf(uc, rrow[s], lg[s]);
    }

    // softmax over s
    float m = lg[0];
    #pragma unroll
    for (int s = 1; s < SS; ++s) m = fmaxf(m, lg[s]);
    float e[SS], sum = 0.f;
    #pragma unroll
    for (int s = 0; s < SS; ++s) { e[s] = __expf(lg[s] - m); sum += e[s]; }
    float inv = 1.f / sum;
    #pragma unroll
    for (int s = 0; s < SS; ++s) att_out[(long)p * SS + s] = e[s] * inv;
}

// ---------------------------------------------------------------------------
// k2: out[n,g,h,w] = sum_{c in g, s} att[h,w,s] * ref[c,h,w,s] * src[n,c,h,w,s]
// block = 256 threads: lane&31 -> w within 32-pixel chunk, lane>>5 -> n.
// The 8 n-threads of one pixel share ref/att lines via L1.
// ---------------------------------------------------------------------------
__global__ __launch_bounds__(256) void k2_out(const float* __restrict__ f,
                                              const float* __restrict__ att,
                                              float* __restrict__ out) {
    int t  = threadIdx.x;
    int wi = t & 31;
    int n  = t >> 5;            // 0..7
    int w  = blockIdx.x * 32 + wi;
    int h  = blockIdx.y;
    const long pix  = (long)h * WW + w;
    const long base = (long)h * F_SH + (long)w * SS;

    float a[SS];
    #pragma unroll
    for (int s = 0; s < SS; ++s) a[s] = att[pix * SS + s];

    const float* refp = f + base;                        // f[0]
    const float* srcp = f + (long)(n + 1) * F_SN + base; // f[n+1]

    float acc[GG];
    #pragma unroll
    for (int g = 0; g < GG; ++g) {
        float ag = 0.f;
        #pragma unroll
        for (int cc = 0; cc < 4; ++cc) {
            int c = g * 4 + cc;
            const float* rr = refp + (long)c * F_SC;
            const float* sr = srcp + (long)c * F_SC;
            #pragma unroll
            for (int s = 0; s < SS; ++s) {
                float ar = a[s] * rr[s];
                ag = fmaf(ar, sr[s], ag);
            }
        }
        acc[g] = ag;
    }

    #pragma unroll
    for (int g = 0; g < GG; ++g)
        out[(((long)n * GG + g) * HH + h) * WW + w] = acc[g];
}

// ---------------------------------------------------------------------------
extern "C" void kernel_launch(void* const* d_in, const int* in_sizes, int n_in,
                              void* d_out, int out_size, void* d_ws, size_t ws_size,
                              hipStream_t stream) {
    const float* f  = (const float*)d_in[0];
    const float* Wp = (const float*)d_in[1];
    const float* bp = (const float*)d_in[2];
    // d_in[3] = o (unused by reference math), d_in[4] = G (fixed 8)
    float* out = (float*)d_out;
    float* ws  = (float*)d_ws;
    float* att = ws + WS_ATT;

    k0_precompute<<<1, 256, 0, stream>>>(Wp, bp, ws);

    // 192*256 pixels / 64 = 768 blocks
    k1_att<<<768, 64, 0, stream>>>(f, ws, att);

    // grid: 8 w-chunks x 192 rows, 256 threads (8n x 32w)
    k2_out<<<dim3(WW / 32, HH), 256, 0, stream>>>(f, att, out);
}

// Round 2
// 664.994 us; speedup vs baseline: 1.0372x; 1.0372x over previous
//
#include <hip/hip_runtime.h>
#include <math.h>

// Problem constants (from reference setup_inputs)
#define NSRC 8          // N-1 source frames
#define CCH  32         // channels
#define HH   192
#define WW   256
#define SS   9
#define GG   8

// f strides in floats: (N, C, H, W, S) contiguous
#define F_SC (HH*WW*SS)        // 442368
#define F_SH (WW*SS)           // 2304
#define F_SN (CCH*HH*WW*SS)    // 14155776

// workspace layout (floats)
#define WS_M   0      // 32x32  M' = Wp^T Wp / sqrt(C)
#define WS_V   1024   // 32     v' = Wp^T bp / sqrt(C)
#define WS_BB  1056   // 1      bb' = |bp|^2 / sqrt(C)

// ---------------------------------------------------------------------------
// k0: tiny precompute of M', v', bb'  (rewritten every call; ws is re-poisoned)
// ---------------------------------------------------------------------------
__global__ void k0_precompute(const float* __restrict__ Wp,
                              const float* __restrict__ bp,
                              float* __restrict__ ws) {
    const float inv_sqrtC = 0.17677669529663687f;  // 1/sqrt(32)
    int t = threadIdx.x;
    for (int idx = t; idx < 1024; idx += 256) {
        int c = idx >> 5, c2 = idx & 31;
        float acc = 0.f;
        for (int d = 0; d < 32; ++d) acc = fmaf(Wp[d*32 + c], Wp[d*32 + c2], acc);
        ws[WS_M + idx] = acc * inv_sqrtC;
    }
    if (t < 32) {
        float acc = 0.f;
        for (int d = 0; d < 32; ++d) acc = fmaf(Wp[d*32 + t], bp[d], acc);
        ws[WS_V + t] = acc * inv_sqrtC;
    }
    if (t == 0) {
        float acc = 0.f;
        for (int d = 0; d < 32; ++d) acc = fmaf(bp[d], bp[d], acc);
        ws[WS_BB] = acc * inv_sqrtC;
    }
}

// ---------------------------------------------------------------------------
// Fused kernel: per 32-pixel chunk — attention (phase 1) + group corr (phase 2)
// Block: 256 threads = (wi 0..31 pixels) x (n 0..7 source frames)
// Grid:  (WW/32, HH)
// ---------------------------------------------------------------------------
__global__ __launch_bounds__(256) void k_fused(const float* __restrict__ f,
                                               const float* __restrict__ ws,
                                               float* __restrict__ out) {
    // LDS
    __shared__ float ref_s[CCH * SS][32];   // [c*9+s][wi] transposed: 36864 B
    __shared__ float M_s[1024];             // 4096 B
    __shared__ float v_s[32];               // 128 B
    __shared__ float bb_s;                  // 4 B
    __shared__ float lgp[32][8][SS];        // partial logits: 9216 B
    __shared__ float pbeta[32][8];          // partial beta:   1024 B
    __shared__ float att_s[32][SS];         // 1152 B

    const int t  = threadIdx.x;
    const int wi = t & 31;
    const int n  = t >> 5;                  // 0..7
    const int w  = blockIdx.x * 32 + wi;
    const int h  = blockIdx.y;
    const long base = (long)h * F_SH + (long)w * SS;

    // ---- stage M', v', bb' (uniform constants) into LDS -------------------
    ((float4*)M_s)[t] = ((const float4*)(ws + WS_M))[t];
    if (t < 32) v_s[t] = ws[WS_V + t];
    if (t == 0) bb_s = ws[WS_BB];

    // ---- phase 1a: load this thread's 4 ref channels (9 floats each) ------
    // keep in registers AND stage to LDS (transposed, conflict-free)
    float rref[4 * SS];
    const float* refp = f + base;
    #pragma unroll
    for (int cc = 0; cc < 4; ++cc) {
        const int c = 4 * n + cc;
        const float* rr = refp + (long)c * F_SC;
        #pragma unroll
        for (int s = 0; s < SS; ++s) {
            float v = rr[s];
            rref[cc * SS + s] = v;
            ref_s[c * SS + s][wi] = v;
        }
    }
    __syncthreads();

    // ---- phase 1b: partial u (4 channels) and partial logits --------------
    float pb = 0.f;
    #pragma unroll
    for (int cc = 0; cc < 4; ++cc)
        pb = fmaf(rref[cc * SS + 4], v_s[4 * n + cc], pb);
    pbeta[wi][n] = pb;

    float u[4];
    #pragma unroll
    for (int cc = 0; cc < 4; ++cc) u[cc] = v_s[4 * n + cc];
    for (int cp = 0; cp < 32; ++cp) {
        float r4 = ref_s[cp * SS + 4][wi];
        #pragma unroll
        for (int cc = 0; cc < 4; ++cc)
            u[cc] = fmaf(M_s[(4 * n + cc) * 32 + cp], r4, u[cc]);
    }

    float lgv[SS];
    #pragma unroll
    for (int s = 0; s < SS; ++s) lgv[s] = 0.f;
    #pragma unroll
    for (int cc = 0; cc < 4; ++cc) {
        float uc = u[cc];
        #pragma unroll
        for (int s = 0; s < SS; ++s)
            lgv[s] = fmaf(uc, rref[cc * SS + s], lgv[s]);
    }
    #pragma unroll
    for (int s = 0; s < SS; ++s) lgp[wi][n][s] = lgv[s];
    __syncthreads();

    // ---- phase 1c: reduce + softmax (32 leader threads) -------------------
    if (n == 0) {
        float lt[SS];
        float beta = bb_s;
        #pragma unroll
        for (int nn = 0; nn < 8; ++nn) beta += pbeta[wi][nn];
        #pragma unroll
        for (int s = 0; s < SS; ++s) lt[s] = beta;
        #pragma unroll
        for (int nn = 0; nn < 8; ++nn)
            #pragma unroll
            for (int s = 0; s < SS; ++s) lt[s] += lgp[wi][nn][s];

        float m = lt[0];
        #pragma unroll
        for (int s = 1; s < SS; ++s) m = fmaxf(m, lt[s]);
        float e[SS], sum = 0.f;
        #pragma unroll
        for (int s = 0; s < SS; ++s) { e[s] = __expf(lt[s] - m); sum += e[s]; }
        float inv = 1.f / sum;
        #pragma unroll
        for (int s = 0; s < SS; ++s) att_s[wi][s] = e[s] * inv;
    }
    __syncthreads();

    // ---- phase 2: group correlation, src streamed from HBM ----------------
    float a[SS];
    #pragma unroll
    for (int s = 0; s < SS; ++s) a[s] = att_s[wi][s];

    const float* srcp = f + (long)(n + 1) * F_SN + base;

    float acc[GG];
    #pragma unroll
    for (int g = 0; g < GG; ++g) {
        float ps[SS];
        #pragma unroll
        for (int s = 0; s < SS; ++s) ps[s] = 0.f;
        #pragma unroll
        for (int cc = 0; cc < 4; ++cc) {
            const int c = g * 4 + cc;
            const float* sr = srcp + (long)c * F_SC;
            #pragma unroll
            for (int s = 0; s < SS; ++s) {
                float rv = ref_s[c * SS + s][wi];
                ps[s] = fmaf(rv, sr[s], ps[s]);
            }
        }
        float ag = 0.f;
        #pragma unroll
        for (int s = 0; s < SS; ++s) ag = fmaf(a[s], ps[s], ag);
        acc[g] = ag;
    }

    #pragma unroll
    for (int g = 0; g < GG; ++g)
        out[(((long)n * GG + g) * HH + h) * WW + w] = acc[g];
}

// ---------------------------------------------------------------------------
extern "C" void kernel_launch(void* const* d_in, const int* in_sizes, int n_in,
                              void* d_out, int out_size, void* d_ws, size_t ws_size,
                              hipStream_t stream) {
    const float* f  = (const float*)d_in[0];
    const float* Wp = (const float*)d_in[1];
    const float* bp = (const float*)d_in[2];
    float* out = (float*)d_out;
    float* ws  = (float*)d_ws;

    k0_precompute<<<1, 256, 0, stream>>>(Wp, bp, ws);
    k_fused<<<dim3(WW / 32, HH), 256, 0, stream>>>(f, ws, out);
}

// Round 3
// 659.476 us; speedup vs baseline: 1.0459x; 1.0084x over previous
//
#include <hip/hip_runtime.h>
#include <math.h>

// Problem constants (from reference setup_inputs)
#define NSRC 8          // N-1 source frames
#define CCH  32         // channels
#define HH   192
#define WW   256
#define SS   9
#define GG   8

// f strides in floats: (N, C, H, W, S) contiguous
#define F_SC (HH*WW*SS)        // 442368
#define F_SH (WW*SS)           // 2304
#define F_SN (CCH*HH*WW*SS)    // 14155776

// workspace layout (floats)
#define WS_M   0      // 32x32  M' = Wp^T Wp / sqrt(C)
#define WS_V   1024   // 32     v' = Wp^T bp / sqrt(C)
#define WS_BB  1056   // 1      bb' = |bp|^2 / sqrt(C)

// tile geometry
#define TILE_W  32
#define ROW_F   (TILE_W * SS)     // 288 floats per channel-row (1152 B, 16B-aligned)
#define TILE_F  (CCH * ROW_F)     // 9216 floats = 36 KB
#define QPT     9                 // float4-quads per thread (2304 quads / 256 thr)

// ---------------------------------------------------------------------------
// k0: tiny precompute of M', v', bb'
// ---------------------------------------------------------------------------
__global__ void k0_precompute(const float* __restrict__ Wp,
                              const float* __restrict__ bp,
                              float* __restrict__ ws) {
    const float inv_sqrtC = 0.17677669529663687f;  // 1/sqrt(32)
    int t = threadIdx.x;
    for (int idx = t; idx < 1024; idx += 256) {
        int c = idx >> 5, c2 = idx & 31;
        float acc = 0.f;
        for (int d = 0; d < 32; ++d) acc = fmaf(Wp[d*32 + c], Wp[d*32 + c2], acc);
        ws[WS_M + idx] = acc * inv_sqrtC;
    }
    if (t < 32) {
        float acc = 0.f;
        for (int d = 0; d < 32; ++d) acc = fmaf(Wp[d*32 + t], bp[d], acc);
        ws[WS_V + t] = acc * inv_sqrtC;
    }
    if (t == 0) {
        float acc = 0.f;
        for (int d = 0; d < 32; ++d) acc = fmaf(bp[d], bp[d], acc);
        ws[WS_BB] = acc * inv_sqrtC;
    }
}

// ---------------------------------------------------------------------------
// Fused kernel. Block = 256 threads = (wi 0..31 pixels) x (j 0..7 channel-quads/groups)
// Grid = (WW/32, HH).
// LDS 36KB buffer staged via global_load_lds (16B DMA), reused ref -> src[0..7].
// ---------------------------------------------------------------------------
__global__ __launch_bounds__(256) void k_fused(const float* __restrict__ f,
                                               const float* __restrict__ ws,
                                               float* __restrict__ out) {
    __shared__ float buf[TILE_F];      // 36 KB: ref tile, then src_n tiles
    __shared__ float M_s[1024];        // 4 KB
    __shared__ float v_s[32];
    __shared__ float bb_s;
    __shared__ float lgp[32 * 73];     // padded partial logits (73: conflict-free)
    __shared__ float att_s[32 * SS];

    const int t  = threadIdx.x;
    const int wi = t & 31;
    const int j  = t >> 5;             // 0..7
    const int wv = t >> 6;             // wave id 0..3
    const int w0 = blockIdx.x * TILE_W;
    const int h  = blockIdx.y;
    const long rowbase = (long)h * F_SH + (long)w0 * SS;  // within a (frame,c) plane

    // ---- stage constants ---------------------------------------------------
    ((float4*)M_s)[t] = ((const float4*)(ws + WS_M))[t];
    if (t < 32) v_s[t] = ws[WS_V + t];
    if (t == 0) bb_s = ws[WS_BB];

    // ---- async tile stage: frame plane -> buf (global-mirror layout) -------
    // quad q = i*256 + t ; c = q/72 ; k = q%72 ; LDS dest = 16*q = base + lane*16
    auto stage = [&](const float* fr) {
        #pragma unroll
        for (int i = 0; i < QPT; ++i) {
            int q = i * 256 + t;
            int c = q / 72;
            int k = q - c * 72;
            const float* g = fr + (long)c * F_SC + rowbase + 4 * k;
            float* l = buf + (i * 1024 + wv * 256);   // wave-uniform; +lane*16B implicit
            __builtin_amdgcn_global_load_lds(
                (const __attribute__((address_space(1))) void*)g,
                (__attribute__((address_space(3))) void*)l,
                16, 0, 0);
        }
    };

    stage(f);                 // ref = frame 0
    __syncthreads();          // S1: ref + consts visible (barrier drains vmcnt)

    // ---- phase 1: own 4 ref channels -> regs; partial u, partial logits ----
    float rref[4 * SS];
    #pragma unroll
    for (int cc = 0; cc < 4; ++cc) {
        const int c = 4 * j + cc;
        #pragma unroll
        for (int s = 0; s < SS; ++s)
            rref[cc * SS + s] = buf[c * ROW_F + wi * SS + s];
    }

    float u[4];
    #pragma unroll
    for (int cc = 0; cc < 4; ++cc) u[cc] = v_s[4 * j + cc];
    #pragma unroll
    for (int cp = 0; cp < 32; ++cp) {
        float r4 = buf[cp * ROW_F + wi * SS + 4];
        #pragma unroll
        for (int cc = 0; cc < 4; ++cc)
            u[cc] = fmaf(M_s[(4 * j + cc) * 32 + cp], r4, u[cc]);
    }

    float pb = 0.f;   // partial beta, folded into partial logits
    #pragma unroll
    for (int cc = 0; cc < 4; ++cc) pb = fmaf(rref[cc * SS + 4], v_s[4 * j + cc], pb);

    float lgv[SS];
    #pragma unroll
    for (int s = 0; s < SS; ++s) lgv[s] = pb;
    #pragma unroll
    for (int cc = 0; cc < 4; ++cc) {
        float uc = u[cc];
        #pragma unroll
        for (int s = 0; s < SS; ++s) lgv[s] = fmaf(uc, rref[cc * SS + s], lgv[s]);
    }
    #pragma unroll
    for (int s = 0; s < SS; ++s) lgp[wi * 73 + j * SS + s] = lgv[s];
    __syncthreads();          // S2: partials visible; all ref LDS reads done

    // ---- softmax (32 leaders) + issue src[0] stage into freed buffer -------
    if (j == 0) {
        float lt[SS];
        #pragma unroll
        for (int s = 0; s < SS; ++s) lt[s] = bb_s;
        #pragma unroll
        for (int jj = 0; jj < 8; ++jj)
            #pragma unroll
            for (int s = 0; s < SS; ++s) lt[s] += lgp[wi * 73 + jj * SS + s];
        float m = lt[0];
        #pragma unroll
        for (int s = 1; s < SS; ++s) m = fmaxf(m, lt[s]);
        float e[SS], sum = 0.f;
        #pragma unroll
        for (int s = 0; s < SS; ++s) { e[s] = __expf(lt[s] - m); sum += e[s]; }
        float inv = 1.f / sum;
        #pragma unroll
        for (int s = 0; s < SS; ++s) att_s[wi * SS + s] = e[s] * inv;
    }
    stage(f + (long)1 * F_SN);        // src n=0 (frame 1)
    __syncthreads();          // S3: att + src0 visible

    // ---- build q = att * ref (registers) -----------------------------------
    float a[SS];
    #pragma unroll
    for (int s = 0; s < SS; ++s) a[s] = att_s[wi * SS + s];
    float qv[4 * SS];
    #pragma unroll
    for (int cc = 0; cc < 4; ++cc)
        #pragma unroll
        for (int s = 0; s < SS; ++s)
            qv[cc * SS + s] = a[s] * rref[cc * SS + s];

    // ---- phase 2: 8 stage/compute rounds ------------------------------------
    #pragma unroll 1
    for (int n = 0; n < NSRC; ++n) {
        float acc = 0.f;
        #pragma unroll
        for (int cc = 0; cc < 4; ++cc) {
            const int c = 4 * j + cc;
            #pragma unroll
            for (int s = 0; s < SS; ++s)
                acc = fmaf(qv[cc * SS + s], buf[c * ROW_F + wi * SS + s], acc);
        }
        out[(((long)n * GG + j) * HH + h) * WW + w0 + wi] = acc;
        if (n < NSRC - 1) {
            __syncthreads();                      // all reads of buf done
            stage(f + (long)(n + 2) * F_SN);      // next src frame
            __syncthreads();                      // staged visible
        }
    }
}

// ---------------------------------------------------------------------------
extern "C" void kernel_launch(void* const* d_in, const int* in_sizes, int n_in,
                              void* d_out, int out_size, void* d_ws, size_t ws_size,
                              hipStream_t stream) {
    const float* f  = (const float*)d_in[0];
    const float* Wp = (const float*)d_in[1];
    const float* bp = (const float*)d_in[2];
    float* out = (float*)d_out;
    float* ws  = (float*)d_ws;

    k0_precompute<<<1, 256, 0, stream>>>(Wp, bp, ws);
    k_fused<<<dim3(WW / TILE_W, HH), 256, 0, stream>>>(f, ws, out);
}